// Round 1
// baseline (968.904 us; speedup 1.0000x reference)
//
#include <hip/hip_runtime.h>
#include <hip/hip_bf16.h>

// Problem shape (fixed by reference setup_inputs)
constexpr int MM = 4096;   // tokens
constexpr int NN = 8192;   // outfeatures
constexpr int KK = 8192;   // infeatures
// GROUP_SIZE = 128, BITS = 4, PACK = 8

constexpr int BM = 256, BN = 256, BK = 64;
constexpr int THREADS = 512;   // 8 waves: 4 along M x 2 along N; wave tile 64x128

typedef __bf16 bf16;
typedef __attribute__((ext_vector_type(8))) __bf16 bf16x8;
typedef __attribute__((ext_vector_type(4))) float floatx4;

__global__ __launch_bounds__(THREADS, 2)
void qgemm_kernel(const float* __restrict__ x,
                  const unsigned* __restrict__ qweight,
                  const unsigned* __restrict__ qzeros,
                  const float* __restrict__ scales,
                  const float* __restrict__ bias,
                  float* __restrict__ out)
{
    // LDS: [row][k] with k contiguous (8-elem/16B chunks), XOR-swizzled chunks
    // so stride-128B rows don't all land on the same banks.
    __shared__ bf16 As[BM * BK];   // 32 KB
    __shared__ bf16 Bs[BN * BK];   // 32 KB

    const int t = threadIdx.x;
    const int ntile = blockIdx.x & 31;   // n fastest: consecutive blocks share x m-tile
    const int mtile = blockIdx.x >> 5;
    const int m0 = mtile * BM;
    const int n0 = ntile * BN;

    // wave geometry
    const int wave = t >> 6;
    const int lane = t & 63;
    const int wm = (wave >> 1) * 64;    // 4 waves along M
    const int wn = (wave & 1) * 128;    // 2 waves along N
    const int ml = lane & 15;
    const int quad = lane >> 4;

    // B staging: each thread owns one output column (n) and 4 qweight rows
    const int bn = t & 255;
    const int rbase = (t >> 8) * 4;     // 0 or 4
    const int gn = n0 + bn;             // global column

    floatx4 acc[4][8];
    for (int i = 0; i < 4; ++i)
        for (int j = 0; j < 8; ++j)
            acc[i][j] = (floatx4){0.f, 0.f, 0.f, 0.f};

    float s = 0.f, sz = 0.f;

    for (int kb = 0; kb < KK / BK; ++kb) {
        const int k0 = kb * BK;

        // group changes every 2 K-blocks (GROUP_SIZE=128, BK=64)
        if ((kb & 1) == 0) {
            const int g = kb >> 1;
            s = scales[g * NN + gn];
            const unsigned zw = qzeros[g * (NN / 8) + (gn >> 3)];
            const float z = (float)(((zw >> (4 * (gn & 7))) & 15u) + 1u);
            sz = s * z;
        }

        // ---- stage A: x fp32 -> bf16 into LDS ----
        // 256 rows x 8 chunks(16B) = 2048 chunks / 512 thr = 4 each
#pragma unroll
        for (int i = 0; i < 4; ++i) {
            const int chunk = t + THREADS * i;
            const int m = chunk >> 3;
            const int c = chunk & 7;
            const float4* src = (const float4*)(x + (size_t)(m0 + m) * KK + (k0 + c * 8));
            const float4 f0 = src[0];
            const float4 f1 = src[1];
            bf16x8 v;
            v[0] = (bf16)f0.x; v[1] = (bf16)f0.y; v[2] = (bf16)f0.z; v[3] = (bf16)f0.w;
            v[4] = (bf16)f1.x; v[5] = (bf16)f1.y; v[6] = (bf16)f1.z; v[7] = (bf16)f1.w;
            *(bf16x8*)&As[m * BK + ((c ^ (m & 7)) << 3)] = v;
        }

        // ---- stage B: unpack 4-bit, dequant to bf16 into LDS ----
        // qweight tile: 8 rows x 256 cols = 2048 int32 / 512 thr = 4 each
        const int kq0 = k0 >> 3;
#pragma unroll
        for (int i = 0; i < 4; ++i) {
            const int rq = rbase + i;
            const unsigned q = qweight[(size_t)(kq0 + rq) * NN + gn];
            bf16x8 v;
#pragma unroll
            for (int j = 0; j < 8; ++j) {
                const float f = (float)((q >> (4 * j)) & 15u) * s - sz;
                v[j] = (bf16)f;
            }
            *(bf16x8*)&Bs[bn * BK + ((rq ^ (bn & 7)) << 3)] = v;
        }

        __syncthreads();

        // ---- MFMA compute: 2 k-steps of 32 ----
#pragma unroll
        for (int ks = 0; ks < 2; ++ks) {
            const int clog = ks * 4 + quad;
            bf16x8 af[4];
            bf16x8 bfr[8];
#pragma unroll
            for (int im = 0; im < 4; ++im) {
                const int row = wm + im * 16 + ml;
                af[im] = *(const bf16x8*)&As[row * BK + ((clog ^ (row & 7)) << 3)];
            }
#pragma unroll
            for (int jn = 0; jn < 8; ++jn) {
                const int row = wn + jn * 16 + ml;
                bfr[jn] = *(const bf16x8*)&Bs[row * BK + ((clog ^ (row & 7)) << 3)];
            }
#pragma unroll
            for (int im = 0; im < 4; ++im)
#pragma unroll
                for (int jn = 0; jn < 8; ++jn)
                    acc[im][jn] = __builtin_amdgcn_mfma_f32_16x16x32_bf16(
                        af[im], bfr[jn], acc[im][jn], 0, 0, 0);
        }

        __syncthreads();
    }

    // ---- epilogue: C/D layout col=lane&15, row=quad*4+reg; add bias ----
#pragma unroll
    for (int jn = 0; jn < 8; ++jn) {
        const int ngl = n0 + wn + jn * 16 + ml;
        const float bv = bias[ngl];
#pragma unroll
        for (int im = 0; im < 4; ++im) {
            const int mg = m0 + wm + im * 16 + quad * 4;
#pragma unroll
            for (int r = 0; r < 4; ++r)
                out[(size_t)(mg + r) * NN + ngl] = acc[im][jn][r] + bv;
        }
    }
}

extern "C" void kernel_launch(void* const* d_in, const int* in_sizes, int n_in,
                              void* d_out, int out_size, void* d_ws, size_t ws_size,
                              hipStream_t stream) {
    const float*    x       = (const float*)d_in[0];
    const unsigned* qweight = (const unsigned*)d_in[1];
    const unsigned* qzeros  = (const unsigned*)d_in[2];
    const float*    scales  = (const float*)d_in[3];
    const float*    bias    = (const float*)d_in[4];
    float* out = (float*)d_out;

    const int grid = (MM / BM) * (NN / BN);   // 16 * 32 = 512 blocks
    qgemm_kernel<<<grid, THREADS, 0, stream>>>(x, qweight, qzeros, scales, bias, out);
}

// Round 2
// 752.147 us; speedup vs baseline: 1.2882x; 1.2882x over previous
//
#include <hip/hip_runtime.h>
#include <hip/hip_bf16.h>

// Problem shape (fixed by reference setup_inputs)
constexpr int MM = 4096;   // tokens
constexpr int NN = 8192;   // outfeatures
constexpr int KK = 8192;   // infeatures
constexpr int BM = 256, BN = 256, BK = 64;
constexpr int THREADS = 512;   // 8 waves: 4 along M x 2 along N; wave tile 64x128
constexpr int NKB = KK / BK;   // 128
constexpr int NT = NN / BN;    // 32

typedef __bf16 bf16;
typedef __attribute__((ext_vector_type(8))) __bf16 bf16x8;
typedef __attribute__((ext_vector_type(4))) float floatx4;

__device__ __forceinline__ void async_copy16(const void* g, void* l) {
    __builtin_amdgcn_global_load_lds(
        (const __attribute__((address_space(1))) void*)g,
        (__attribute__((address_space(3))) void*)l, 16, 0, 0);
}

// ---------------------------------------------------------------------------
// Prep: x fp32 -> bf16, re-laid-out tile-major [mtile][kb][m][chunk^swizzle]
// so each (mtile,kb) A-tile (32 KB) is byte-identical to its LDS image and
// can be staged with global_load_lds DMA.
// ---------------------------------------------------------------------------
__global__ __launch_bounds__(256)
void convert_x(const float* __restrict__ x, bf16* __restrict__ xb) {
    const int tid = blockIdx.x * 256 + threadIdx.x;   // one 16B chunk (8 elems)
    const int c = tid & 7;
    const int m = (tid >> 3) & 255;
    const int kb = (tid >> 11) & 127;
    const int mtile = tid >> 18;
    const int row = mtile * 256 + m;
    const int col = kb * 64 + c * 8;
    const float4* src = (const float4*)(x + (size_t)row * KK + col);
    const float4 f0 = src[0];
    const float4 f1 = src[1];
    bf16x8 v;
    v[0] = (bf16)f0.x; v[1] = (bf16)f0.y; v[2] = (bf16)f0.z; v[3] = (bf16)f0.w;
    v[4] = (bf16)f1.x; v[5] = (bf16)f1.y; v[6] = (bf16)f1.z; v[7] = (bf16)f1.w;
    const int dst_chunk = (tid & ~7) | (c ^ (m & 7));
    *(bf16x8*)(xb + (size_t)dst_chunk * 8) = v;
}

// ---------------------------------------------------------------------------
// Main GEMM: double-buffered LDS, one barrier per K-block.
//   iter kb: issue A-DMA + B prefetch for kb+1 -> compute kb -> dequant-store
//   B(kb+1) -> barrier.  The compiler's vmcnt(0)-before-s_barrier drain lands
//   after ~2500 cyc of MFMA, so the DMA latency is hidden.
// ---------------------------------------------------------------------------
__global__ __launch_bounds__(THREADS, 2)
void qgemm_dma(const bf16* __restrict__ xb,
               const unsigned* __restrict__ qweight,
               const unsigned* __restrict__ qzeros,
               const float* __restrict__ scales,
               const float* __restrict__ bias,
               float* __restrict__ out)
{
    __shared__ alignas(16) bf16 As[2][BM * BK];   // 2 x 32 KB
    __shared__ alignas(16) bf16 Bs[2][BN * BK];   // 2 x 32 KB

    const int t = threadIdx.x;
    const int ntile = blockIdx.x & (NT - 1);   // n fastest: share x m-tile
    const int mtile = blockIdx.x / NT;
    const int n0 = ntile * BN;

    const int wave = t >> 6;
    const int lane = t & 63;
    const int wm = (wave >> 1) * 64;    // 4 waves along M
    const int wn = (wave & 1) * 128;    // 2 waves along N
    const int ml = lane & 15;
    const int quad = lane >> 4;

    // B staging: each thread owns one output column and 4 qweight rows
    const int bn = t & 255;
    const int rbase = (t >> 8) * 4;     // 0 or 4
    const int gn = n0 + bn;

    floatx4 acc[4][8];
#pragma unroll
    for (int i = 0; i < 4; ++i)
#pragma unroll
        for (int j = 0; j < 8; ++j)
            acc[i][j] = (floatx4){0.f, 0.f, 0.f, 0.f};

    const char* xb_base = (const char*)xb
        + (size_t)mtile * NKB * (BM * BK) * sizeof(bf16);

    unsigned bq[4];
    float s = 0.f, sz = 0.f;

    // --- helpers ---
    auto stage_a = [&](int kb, int buf) {
        const char* g = xb_base + (size_t)kb * (BM * BK * 2) + wave * 4096 + lane * 16;
        char* l = (char*)&As[buf][0] + wave * 4096;
#pragma unroll
        for (int i = 0; i < 4; ++i)
            async_copy16(g + i * 1024, l + i * 1024);
    };
    auto load_b = [&](int kb) {
#pragma unroll
        for (int i = 0; i < 4; ++i)
            bq[i] = qweight[(size_t)(kb * 8 + rbase + i) * NN + gn];
    };
    auto store_b = [&](int buf) {
#pragma unroll
        for (int i = 0; i < 4; ++i) {
            const int rq = rbase + i;
            bf16x8 v;
#pragma unroll
            for (int j = 0; j < 8; ++j)
                v[j] = (bf16)((float)((bq[i] >> (4 * j)) & 15u) * s - sz);
            *(bf16x8*)&Bs[buf][bn * BK + ((rq ^ (bn & 7)) << 3)] = v;
        }
    };
    auto compute = [&](int buf) {
#pragma unroll
        for (int ks = 0; ks < 2; ++ks) {
            const int clog = ks * 4 + quad;
            bf16x8 af[4];
#pragma unroll
            for (int im = 0; im < 4; ++im) {
                const int row = wm + im * 16 + ml;
                af[im] = *(const bf16x8*)&As[buf][row * BK + ((clog ^ (row & 7)) << 3)];
            }
#pragma unroll
            for (int jh = 0; jh < 2; ++jh) {   // split B frags: reg pressure
                bf16x8 bf4[4];
#pragma unroll
                for (int j = 0; j < 4; ++j) {
                    const int row = wn + (jh * 4 + j) * 16 + ml;
                    bf4[j] = *(const bf16x8*)&Bs[buf][row * BK + ((clog ^ (row & 7)) << 3)];
                }
#pragma unroll
                for (int im = 0; im < 4; ++im)
#pragma unroll
                    for (int j = 0; j < 4; ++j)
                        acc[im][jh * 4 + j] = __builtin_amdgcn_mfma_f32_16x16x32_bf16(
                            af[im], bf4[j], acc[im][jh * 4 + j], 0, 0, 0);
            }
        }
    };

    // --- prologue: stage kb=0 into buf 0 ---
    {
        s = scales[gn];                      // group 0
        const unsigned zw = qzeros[gn >> 3];
        sz = s * (float)(((zw >> (4 * (gn & 7))) & 15u) + 1u);
        stage_a(0, 0);
        load_b(0);
        store_b(0);
    }
    __syncthreads();

    float s_nxt = 0.f;
    unsigned zw_nxt = 0;
    for (int kb = 0; kb < NKB; ++kb) {
        const int p = kb & 1, q = p ^ 1;
        const bool has_next = (kb + 1) < NKB;
        if (has_next) {
            stage_a(kb + 1, q);              // DMA into other buffer
            load_b(kb + 1);                  // raw qweight into regs
            if (((kb + 1) & 1) == 0) {       // group changes every 2 K-blocks
                const int g = (kb + 1) >> 1;
                s_nxt = scales[(size_t)g * NN + gn];
                zw_nxt = qzeros[(size_t)g * (NN / 8) + (gn >> 3)];
            }
        }
        compute(p);
        if (has_next) {
            if (((kb + 1) & 1) == 0) {
                s = s_nxt;
                sz = s * (float)(((zw_nxt >> (4 * (gn & 7))) & 15u) + 1u);
            }
            store_b(q);
            __syncthreads();                 // the single barrier per K-block
        }
    }

    // --- epilogue: C/D layout col=lane&15, row=quad*4+reg; add bias ---
#pragma unroll
    for (int jn = 0; jn < 8; ++jn) {
        const int ngl = n0 + wn + jn * 16 + ml;
        const float bv = bias[ngl];
#pragma unroll
        for (int im = 0; im < 4; ++im) {
            const int mg = mtile * BM + wm + im * 16 + quad * 4;
#pragma unroll
            for (int r = 0; r < 4; ++r)
                out[(size_t)(mg + r) * NN + ngl] = acc[im][jn][r] + bv;
        }
    }
}

// ---------------------------------------------------------------------------
// Fallback (round-1 kernel, known-good): used only if ws is too small for xb.
// ---------------------------------------------------------------------------
__global__ __launch_bounds__(THREADS, 2)
void qgemm_fallback(const float* __restrict__ x,
                    const unsigned* __restrict__ qweight,
                    const unsigned* __restrict__ qzeros,
                    const float* __restrict__ scales,
                    const float* __restrict__ bias,
                    float* __restrict__ out)
{
    __shared__ bf16 As[BM * BK];
    __shared__ bf16 Bs[BN * BK];

    const int t = threadIdx.x;
    const int ntile = blockIdx.x & 31;
    const int mtile = blockIdx.x >> 5;
    const int m0 = mtile * BM;
    const int n0 = ntile * BN;
    const int wave = t >> 6;
    const int lane = t & 63;
    const int wm = (wave >> 1) * 64;
    const int wn = (wave & 1) * 128;
    const int ml = lane & 15;
    const int quad = lane >> 4;
    const int bn = t & 255;
    const int rbase = (t >> 8) * 4;
    const int gn = n0 + bn;

    floatx4 acc[4][8];
    for (int i = 0; i < 4; ++i)
        for (int j = 0; j < 8; ++j)
            acc[i][j] = (floatx4){0.f, 0.f, 0.f, 0.f};

    float s = 0.f, sz = 0.f;

    for (int kb = 0; kb < KK / BK; ++kb) {
        const int k0 = kb * BK;
        if ((kb & 1) == 0) {
            const int g = kb >> 1;
            s = scales[g * NN + gn];
            const unsigned zw = qzeros[g * (NN / 8) + (gn >> 3)];
            const float z = (float)(((zw >> (4 * (gn & 7))) & 15u) + 1u);
            sz = s * z;
        }
#pragma unroll
        for (int i = 0; i < 4; ++i) {
            const int chunk = t + THREADS * i;
            const int m = chunk >> 3;
            const int c = chunk & 7;
            const float4* src = (const float4*)(x + (size_t)(m0 + m) * KK + (k0 + c * 8));
            const float4 f0 = src[0];
            const float4 f1 = src[1];
            bf16x8 v;
            v[0] = (bf16)f0.x; v[1] = (bf16)f0.y; v[2] = (bf16)f0.z; v[3] = (bf16)f0.w;
            v[4] = (bf16)f1.x; v[5] = (bf16)f1.y; v[6] = (bf16)f1.z; v[7] = (bf16)f1.w;
            *(bf16x8*)&As[m * BK + ((c ^ (m & 7)) << 3)] = v;
        }
        const int kq0 = k0 >> 3;
#pragma unroll
        for (int i = 0; i < 4; ++i) {
            const int rq = rbase + i;
            const unsigned q = qweight[(size_t)(kq0 + rq) * NN + gn];
            bf16x8 v;
#pragma unroll
            for (int j = 0; j < 8; ++j) {
                const float f = (float)((q >> (4 * j)) & 15u) * s - sz;
                v[j] = (bf16)f;
            }
            *(bf16x8*)&Bs[bn * BK + ((rq ^ (bn & 7)) << 3)] = v;
        }
        __syncthreads();
#pragma unroll
        for (int ks = 0; ks < 2; ++ks) {
            const int clog = ks * 4 + quad;
            bf16x8 af[4];
            bf16x8 bfr[8];
#pragma unroll
            for (int im = 0; im < 4; ++im) {
                const int row = wm + im * 16 + ml;
                af[im] = *(const bf16x8*)&As[row * BK + ((clog ^ (row & 7)) << 3)];
            }
#pragma unroll
            for (int jn = 0; jn < 8; ++jn) {
                const int row = wn + jn * 16 + ml;
                bfr[jn] = *(const bf16x8*)&Bs[row * BK + ((clog ^ (row & 7)) << 3)];
            }
#pragma unroll
            for (int im = 0; im < 4; ++im)
#pragma unroll
                for (int jn = 0; jn < 8; ++jn)
                    acc[im][jn] = __builtin_amdgcn_mfma_f32_16x16x32_bf16(
                        af[im], bfr[jn], acc[im][jn], 0, 0, 0);
        }
        __syncthreads();
    }
#pragma unroll
    for (int jn = 0; jn < 8; ++jn) {
        const int ngl = n0 + wn + jn * 16 + ml;
        const float bv = bias[ngl];
#pragma unroll
        for (int im = 0; im < 4; ++im) {
            const int mg = m0 + wm + im * 16 + quad * 4;
#pragma unroll
            for (int r = 0; r < 4; ++r)
                out[(size_t)(mg + r) * NN + ngl] = acc[im][jn][r] + bv;
        }
    }
}

extern "C" void kernel_launch(void* const* d_in, const int* in_sizes, int n_in,
                              void* d_out, int out_size, void* d_ws, size_t ws_size,
                              hipStream_t stream) {
    const float*    x       = (const float*)d_in[0];
    const unsigned* qweight = (const unsigned*)d_in[1];
    const unsigned* qzeros  = (const unsigned*)d_in[2];
    const float*    scales  = (const float*)d_in[3];
    const float*    bias    = (const float*)d_in[4];
    float* out = (float*)d_out;

    const int grid = (MM / BM) * (NN / BN);   // 512 blocks
    const size_t xb_bytes = (size_t)MM * KK * sizeof(bf16);   // 67 MB

    if (ws_size >= xb_bytes) {
        bf16* xb = (bf16*)d_ws;
        const int chunks = MM * KK / 8;       // 4,194,304
        convert_x<<<chunks / 256, 256, 0, stream>>>(x, xb);
        qgemm_dma<<<grid, THREADS, 0, stream>>>(xb, qweight, qzeros, scales, bias, out);
    } else {
        qgemm_fallback<<<grid, THREADS, 0, stream>>>(x, qweight, qzeros, scales, bias, out);
    }
}